// Round 1
// baseline (421.439 us; speedup 1.0000x reference)
//
#include <hip/hip_runtime.h>
#include <math.h>

// Problem: x (2,16,2048,2048) fp32.
// Outputs (flat fp32 concat in d_out):
//   out  = softmax(x, axis=-1)                       [134217728]
//   q    = blockwise 64x64 int8 quant (as floats)    [134217728]
//   s    = per-block scale                           [32768]
//   z    = per-block zero point                      [32768]
// Block index b = n*1024 + i*32 + j over (N=32, g1=32, g2=32);
// within block: row-major 64x64 of the tile.

static constexpr int  COLS      = 2048;
static constexpr long long OUT_ELEMS = 134217728LL;  // 2*16*2048*2048
static constexpr int  NROWS     = 65536;              // 32 * 2048
static constexpr int  NBLK      = 32768;              // 32 * 32 * 32

// ---------------- Kernel 1: per-row max and 1/sum(exp(x-max)) ----------------
// One wave (64 lanes) per row; 4 rows per 256-thread block.
// Each lane holds 32 contiguous-strided floats (8 x float4) in registers.
__global__ __launch_bounds__(256) void rowstats_kernel(
    const float* __restrict__ x, float* __restrict__ stats)
{
    const int lane = threadIdx.x & 63;
    const int wave = threadIdx.x >> 6;
    const long long row = (long long)blockIdx.x * 4 + wave;
    const float* rp = x + row * COLS;

    float4 v[8];
#pragma unroll
    for (int c = 0; c < 8; ++c)
        v[c] = *reinterpret_cast<const float4*>(rp + c * 256 + lane * 4);

    float m = -INFINITY;
#pragma unroll
    for (int c = 0; c < 8; ++c)
        m = fmaxf(m, fmaxf(fmaxf(v[c].x, v[c].y), fmaxf(v[c].z, v[c].w)));
#pragma unroll
    for (int off = 32; off >= 1; off >>= 1)
        m = fmaxf(m, __shfl_xor(m, off, 64));

    float s = 0.0f;
#pragma unroll
    for (int c = 0; c < 8; ++c)
        s += expf(v[c].x - m) + expf(v[c].y - m) +
             expf(v[c].z - m) + expf(v[c].w - m);
#pragma unroll
    for (int off = 32; off >= 1; off >>= 1)
        s += __shfl_xor(s, off, 64);

    if (lane == 0) {
        stats[row * 2 + 0] = m;
        stats[row * 2 + 1] = 1.0f / s;
    }
}

// ---------------- Kernel 2: per-64x64-tile softmax + quantize ----------------
// One 256-thread block per tile. Thread t handles float4 columns
// [(t&15)*4, +4) of rows (t>>4) + {0,16,32,48}.
__global__ __launch_bounds__(256) void tile_kernel(
    const float* __restrict__ x, const float* __restrict__ stats,
    float* __restrict__ out, float* __restrict__ qout,
    float* __restrict__ sout, float* __restrict__ zout)
{
    const int b = blockIdx.x;          // 0..32767
    const int n = b >> 10;             // outer batch (32)
    const int i = (b >> 5) & 31;       // row-block
    const int j = b & 31;              // col-block
    const int t = threadIdx.x;
    const int col4 = (t & 15) * 4;     // column offset within tile
    const int r0 = t >> 4;             // base row 0..15

    const long long xbase = (long long)n * (COLS * (long long)COLS)
                          + (long long)(i * 64) * COLS + j * 64;
    const int growbase = (n << 11) + i * 64;   // global row index base

    float4 p[4];
    float mn = INFINITY, mx = -INFINITY;
#pragma unroll
    for (int k = 0; k < 4; ++k) {
        const int r = r0 + k * 16;
        const float2 st = *reinterpret_cast<const float2*>(
            stats + (long long)(growbase + r) * 2);
        const float4 v = *reinterpret_cast<const float4*>(
            x + xbase + (long long)r * COLS + col4);
        float4 pv;
        pv.x = expf(v.x - st.x) * st.y;
        pv.y = expf(v.y - st.x) * st.y;
        pv.z = expf(v.z - st.x) * st.y;
        pv.w = expf(v.w - st.x) * st.y;
        p[k] = pv;
        mn = fminf(mn, fminf(fminf(pv.x, pv.y), fminf(pv.z, pv.w)));
        mx = fmaxf(mx, fmaxf(fmaxf(pv.x, pv.y), fmaxf(pv.z, pv.w)));
    }
#pragma unroll
    for (int off = 32; off >= 1; off >>= 1) {
        mn = fminf(mn, __shfl_xor(mn, off, 64));
        mx = fmaxf(mx, __shfl_xor(mx, off, 64));
    }

    __shared__ float smn[4], smx[4], sbc[2];   // sbc = {z, 1/(s+eps)}
    const int wave = t >> 6;
    if ((t & 63) == 0) { smn[wave] = mn; smx[wave] = mx; }
    __syncthreads();
    if (t == 0) {
        const float bmn = fminf(fminf(smn[0], smn[1]), fminf(smn[2], smn[3]));
        const float bmx = fmaxf(fmaxf(smx[0], smx[1]), fmaxf(smx[2], smx[3]));
        const float sc = (bmx - bmn) / 255.0f;
        const float d  = sc + 1e-10f;
        const float zz = -bmn / d - 128.0f;
        sout[b] = sc;
        zout[b] = zz;
        sbc[0] = zz;
        sbc[1] = 1.0f / d;
    }
    __syncthreads();
    const float z = sbc[0], rcp = sbc[1];

    float* __restrict__ qb = qout + (long long)b * 4096;
#pragma unroll
    for (int k = 0; k < 4; ++k) {
        const int r = r0 + k * 16;
        const float4 pv = p[k];
        *reinterpret_cast<float4*>(out + xbase + (long long)r * COLS + col4) = pv;
        float4 qv;
        qv.x = roundf(fminf(fmaxf(pv.x * rcp + z, -128.0f), 127.0f));
        qv.y = roundf(fminf(fmaxf(pv.y * rcp + z, -128.0f), 127.0f));
        qv.z = roundf(fminf(fmaxf(pv.z * rcp + z, -128.0f), 127.0f));
        qv.w = roundf(fminf(fmaxf(pv.w * rcp + z, -128.0f), 127.0f));
        *reinterpret_cast<float4*>(qb + r * 64 + col4) = qv;
    }
}

extern "C" void kernel_launch(void* const* d_in, const int* in_sizes, int n_in,
                              void* d_out, int out_size, void* d_ws, size_t ws_size,
                              hipStream_t stream) {
    const float* x = (const float*)d_in[0];
    float* out  = (float*)d_out;
    float* qout = out + OUT_ELEMS;
    float* sout = qout + OUT_ELEMS;
    float* zout = sout + NBLK;
    float* stats = (float*)d_ws;   // NROWS * 2 floats = 512 KB

    rowstats_kernel<<<NROWS / 4, 256, 0, stream>>>(x, stats);
    tile_kernel<<<NBLK, 256, 0, stream>>>(x, stats, out, qout, sout, zout);
}

// Round 2
// 405.957 us; speedup vs baseline: 1.0381x; 1.0381x over previous
//
#include <hip/hip_runtime.h>
#include <math.h>

// x (2,16,2048,2048) fp32 -> d_out flat fp32 concat:
//   out  = softmax(x, -1)                [134217728]
//   q    = 64x64 blockwise int8 (as f32) [134217728]
//   s    = per-block scale               [32768]
//   z    = per-block zero                [32768]

static constexpr int  COLS      = 2048;
static constexpr long long OUT_ELEMS = 134217728LL;
static constexpr int  NROWS     = 65536;   // 32 * 2048
static constexpr int  NBLK      = 32768;   // 32 * 32 * 32

using v4f = __attribute__((ext_vector_type(4))) float;

// ---------------- Kernel 1: per-row max and 1/sum(exp(x-max)) ----------------
__global__ __launch_bounds__(256) void rowstats_kernel(
    const float* __restrict__ x, float* __restrict__ stats)
{
    const int lane = threadIdx.x & 63;
    const int wave = threadIdx.x >> 6;
    const long long row = (long long)blockIdx.x * 4 + wave;
    const float* rp = x + row * COLS;

    float4 v[8];
#pragma unroll
    for (int c = 0; c < 8; ++c)
        v[c] = *reinterpret_cast<const float4*>(rp + c * 256 + lane * 4);

    float m = -INFINITY;
#pragma unroll
    for (int c = 0; c < 8; ++c)
        m = fmaxf(m, fmaxf(fmaxf(v[c].x, v[c].y), fmaxf(v[c].z, v[c].w)));
#pragma unroll
    for (int off = 32; off >= 1; off >>= 1)
        m = fmaxf(m, __shfl_xor(m, off, 64));

    float s = 0.0f;
#pragma unroll
    for (int c = 0; c < 8; ++c)
        s += expf(v[c].x - m) + expf(v[c].y - m) +
             expf(v[c].z - m) + expf(v[c].w - m);
#pragma unroll
    for (int off = 32; off >= 1; off >>= 1)
        s += __shfl_xor(s, off, 64);

    if (lane == 0) {
        stats[row * 2 + 0] = m;
        stats[row * 2 + 1] = 1.0f / s;
    }
}

// ---------------- Kernel 2: 64x256 panel = 4 column-tiles per block ----------
// 8192 blocks of 256 threads. Wave w handles rows {4k+w}, k=0..15; lane l
// covers cols [l*4, l*4+4) of the 256-col panel -> 1 KB contiguous per wave
// for x reads and out writes. Lane's 4 cols live entirely in tile t = l>>4.
__global__ __launch_bounds__(256) void panel_kernel(
    const float* __restrict__ x, const float* __restrict__ stats,
    float* __restrict__ out, float* __restrict__ qout,
    float* __restrict__ sout, float* __restrict__ zout)
{
    const int b  = blockIdx.x;       // 0..8191
    const int n  = b >> 8;           // 0..31
    const int i  = (b >> 3) & 31;    // row-block
    const int jg = b & 7;            // group of 4 column-tiles
    const int t  = threadIdx.x;
    const int w  = t >> 6;           // wave 0..3
    const int l  = t & 63;

    const long long xbase = (long long)n * (COLS * (long long)COLS)
                          + (long long)(i * 64) * COLS + jg * 256;
    const int growbase = (n << 11) + i * 64;

    float4 p[16];
    float mn = INFINITY, mx = -INFINITY;
#pragma unroll
    for (int k = 0; k < 16; ++k) {
        const int r = (k << 2) + w;
        const float2 st = *reinterpret_cast<const float2*>(
            stats + (long long)(growbase + r) * 2);
        const float4 v = *reinterpret_cast<const float4*>(
            x + xbase + (long long)r * COLS + l * 4);
        float4 pv;
        pv.x = expf(v.x - st.x) * st.y;
        pv.y = expf(v.y - st.x) * st.y;
        pv.z = expf(v.z - st.x) * st.y;
        pv.w = expf(v.w - st.x) * st.y;
        p[k] = pv;
        mn = fminf(mn, fminf(fminf(pv.x, pv.y), fminf(pv.z, pv.w)));
        mx = fmaxf(mx, fmaxf(fmaxf(pv.x, pv.y), fmaxf(pv.z, pv.w)));
    }
    // reduce within each 16-lane group (one group per tile)
#pragma unroll
    for (int off = 8; off >= 1; off >>= 1) {
        mn = fminf(mn, __shfl_xor(mn, off, 64));
        mx = fmaxf(mx, __shfl_xor(mx, off, 64));
    }

    __shared__ float  smn[4][4], smx[4][4];   // [wave][tile]
    __shared__ float2 sbc[4];                 // per tile: {z, 1/(s+eps)}
    if ((l & 15) == 0) { smn[w][l >> 4] = mn; smx[w][l >> 4] = mx; }
    __syncthreads();
    if (t < 4) {
        const float bmn = fminf(fminf(smn[0][t], smn[1][t]),
                                fminf(smn[2][t], smn[3][t]));
        const float bmx = fmaxf(fmaxf(smx[0][t], smx[1][t]),
                                fmaxf(smx[2][t], smx[3][t]));
        const float sc = (bmx - bmn) / 255.0f;
        const float d  = sc + 1e-10f;
        const float zz = -bmn / d - 128.0f;
        const int b4 = (n << 10) + (i << 5) + (jg << 2) + t;
        sout[b4] = sc;
        zout[b4] = zz;
        sbc[t] = make_float2(zz, 1.0f / d);
    }
    __syncthreads();

    const int   tl  = l >> 4;
    const float2 bc = sbc[tl];
    float* __restrict__ qb = qout
        + (long long)((n << 10) + (i << 5) + (jg << 2)) * 4096
        + tl * 4096 + (l & 15) * 4;

#pragma unroll
    for (int k = 0; k < 16; ++k) {
        const int r = (k << 2) + w;
        const float4 pv = p[k];
        __builtin_nontemporal_store(*(const v4f*)&pv,
            (v4f*)(out + xbase + (long long)r * COLS + l * 4));
        float4 qv;
        qv.x = roundf(fminf(fmaxf(pv.x * bc.y + bc.x, -128.0f), 127.0f));
        qv.y = roundf(fminf(fmaxf(pv.y * bc.y + bc.x, -128.0f), 127.0f));
        qv.z = roundf(fminf(fmaxf(pv.z * bc.y + bc.x, -128.0f), 127.0f));
        qv.w = roundf(fminf(fmaxf(pv.w * bc.y + bc.x, -128.0f), 127.0f));
        __builtin_nontemporal_store(*(const v4f*)&qv, (v4f*)(qb + r * 64));
    }
}

extern "C" void kernel_launch(void* const* d_in, const int* in_sizes, int n_in,
                              void* d_out, int out_size, void* d_ws, size_t ws_size,
                              hipStream_t stream) {
    const float* x = (const float*)d_in[0];
    float* out  = (float*)d_out;
    float* qout = out + OUT_ELEMS;
    float* sout = qout + OUT_ELEMS;
    float* zout = sout + NBLK;
    float* stats = (float*)d_ws;   // NROWS * 2 floats = 512 KB

    rowstats_kernel<<<NROWS / 4, 256, 0, stream>>>(x, stats);
    panel_kernel<<<8192, 256, 0, stream>>>(x, stats, out, qout, sout, zout);
}

// Round 3
// 404.321 us; speedup vs baseline: 1.0423x; 1.0040x over previous
//
#include <hip/hip_runtime.h>
#include <math.h>

// x (2,16,2048,2048) fp32 -> d_out flat fp32 concat:
//   out  = softmax(x, -1)                [134217728]
//   q    = 64x64 blockwise int8 (as f32) [134217728]
//   s    = per-block scale               [32768]
//   z    = per-block zero                [32768]

static constexpr int  COLS      = 2048;
static constexpr long long OUT_ELEMS = 134217728LL;
static constexpr int  NROWS     = 65536;   // 32 * 2048
static constexpr int  NBLK      = 32768;   // 32 * 32 * 32

using v4f = __attribute__((ext_vector_type(4))) float;

// ---------------- Kernel 1: per-row max and 1/sum(exp(x-max)) ----------------
__global__ __launch_bounds__(256) void rowstats_kernel(
    const float* __restrict__ x, float* __restrict__ stats)
{
    const int lane = threadIdx.x & 63;
    const int wave = threadIdx.x >> 6;
    const long long row = (long long)blockIdx.x * 4 + wave;
    const float* rp = x + row * COLS;

    float4 v[8];
#pragma unroll
    for (int c = 0; c < 8; ++c)
        v[c] = *reinterpret_cast<const float4*>(rp + c * 256 + lane * 4);

    float m = -INFINITY;
#pragma unroll
    for (int c = 0; c < 8; ++c)
        m = fmaxf(m, fmaxf(fmaxf(v[c].x, v[c].y), fmaxf(v[c].z, v[c].w)));
#pragma unroll
    for (int off = 32; off >= 1; off >>= 1)
        m = fmaxf(m, __shfl_xor(m, off, 64));

    float s = 0.0f;
#pragma unroll
    for (int c = 0; c < 8; ++c)
        s += expf(v[c].x - m) + expf(v[c].y - m) +
             expf(v[c].z - m) + expf(v[c].w - m);
#pragma unroll
    for (int off = 32; off >= 1; off >>= 1)
        s += __shfl_xor(s, off, 64);

    if (lane == 0) {
        stats[row * 2 + 0] = m;
        stats[row * 2 + 1] = 1.0f / s;
    }
}

// ---------------- Kernel 2: 64x256 panel = 4 column-tiles per block ----------
// 8192 blocks of 256 threads. Wave w handles rows {4k+w}, k=0..15; lane l
// covers cols [l*4, l*4+4) of the 256-col panel -> 1 KB contiguous per wave
// for x reads and out writes. Lane's 4 cols live entirely in tile t = l>>4.
__global__ __launch_bounds__(256) void panel_kernel(
    const float* __restrict__ x, const float* __restrict__ stats,
    float* __restrict__ out, float* __restrict__ qout,
    float* __restrict__ sout, float* __restrict__ zout)
{
    const int b  = blockIdx.x;       // 0..8191
    const int n  = b >> 8;           // 0..31
    const int i  = (b >> 3) & 31;    // row-block
    const int jg = b & 7;            // group of 4 column-tiles
    const int t  = threadIdx.x;
    const int w  = t >> 6;           // wave 0..3
    const int l  = t & 63;

    const long long xbase = (long long)n * (COLS * (long long)COLS)
                          + (long long)(i * 64) * COLS + jg * 256;
    const int growbase = (n << 11) + i * 64;

    float4 p[16];
    float mn = INFINITY, mx = -INFINITY;
#pragma unroll
    for (int k = 0; k < 16; ++k) {
        const int r = (k << 2) + w;
        const float2 st = *reinterpret_cast<const float2*>(
            stats + (long long)(growbase + r) * 2);
        const float4 v = *reinterpret_cast<const float4*>(
            x + xbase + (long long)r * COLS + l * 4);
        float4 pv;
        pv.x = expf(v.x - st.x) * st.y;
        pv.y = expf(v.y - st.x) * st.y;
        pv.z = expf(v.z - st.x) * st.y;
        pv.w = expf(v.w - st.x) * st.y;
        p[k] = pv;
        mn = fminf(mn, fminf(fminf(pv.x, pv.y), fminf(pv.z, pv.w)));
        mx = fmaxf(mx, fmaxf(fmaxf(pv.x, pv.y), fmaxf(pv.z, pv.w)));
    }
    // reduce within each 16-lane group (one group per tile)
#pragma unroll
    for (int off = 8; off >= 1; off >>= 1) {
        mn = fminf(mn, __shfl_xor(mn, off, 64));
        mx = fmaxf(mx, __shfl_xor(mx, off, 64));
    }

    __shared__ float  smn[4][4], smx[4][4];   // [wave][tile]
    __shared__ float2 sbc[4];                 // per tile: {z, 1/(s+eps)}
    if ((l & 15) == 0) { smn[w][l >> 4] = mn; smx[w][l >> 4] = mx; }
    __syncthreads();
    if (t < 4) {
        const float bmn = fminf(fminf(smn[0][t], smn[1][t]),
                                fminf(smn[2][t], smn[3][t]));
        const float bmx = fmaxf(fmaxf(smx[0][t], smx[1][t]),
                                fmaxf(smx[2][t], smx[3][t]));
        const float sc = (bmx - bmn) / 255.0f;
        const float d  = sc + 1e-10f;
        const float zz = -bmn / d - 128.0f;
        const int b4 = (n << 10) + (i << 5) + (jg << 2) + t;
        sout[b4] = sc;
        zout[b4] = zz;
        sbc[t] = make_float2(zz, 1.0f / d);
    }
    __syncthreads();

    const int   tl  = l >> 4;
    const float2 bc = sbc[tl];
    float* __restrict__ qb = qout
        + (long long)((n << 10) + (i << 5) + (jg << 2)) * 4096
        + tl * 4096 + (l & 15) * 4;

#pragma unroll
    for (int k = 0; k < 16; ++k) {
        const int r = (k << 2) + w;
        const float4 pv = p[k];
        __builtin_nontemporal_store(*(const v4f*)&pv,
            (v4f*)(out + xbase + (long long)r * COLS + l * 4));
        float4 qv;
        qv.x = roundf(fminf(fmaxf(pv.x * bc.y + bc.x, -128.0f), 127.0f));
        qv.y = roundf(fminf(fmaxf(pv.y * bc.y + bc.x, -128.0f), 127.0f));
        qv.z = roundf(fminf(fmaxf(pv.z * bc.y + bc.x, -128.0f), 127.0f));
        qv.w = roundf(fminf(fmaxf(pv.w * bc.y + bc.x, -128.0f), 127.0f));
        __builtin_nontemporal_store(*(const v4f*)&qv, (v4f*)(qb + r * 64));
    }
}

extern "C" void kernel_launch(void* const* d_in, const int* in_sizes, int n_in,
                              void* d_out, int out_size, void* d_ws, size_t ws_size,
                              hipStream_t stream) {
    const float* x = (const float*)d_in[0];
    float* out  = (float*)d_out;
    float* qout = out + OUT_ELEMS;
    float* sout = qout + OUT_ELEMS;
    float* zout = sout + NBLK;
    float* stats = (float*)d_ws;   // NROWS * 2 floats = 512 KB

    rowstats_kernel<<<NROWS / 4, 256, 0, stream>>>(x, stats);
    panel_kernel<<<8192, 256, 0, stream>>>(x, stats, out, qout, sout, zout);
}

// Round 4
// 356.478 us; speedup vs baseline: 1.1822x; 1.1342x over previous
//
#include <hip/hip_runtime.h>
#include <math.h>

// x (2,16,2048,2048) fp32 -> d_out flat fp32 concat:
//   out  = softmax(x, -1)                [134217728]
//   q    = 64x64 blockwise int8 (as f32) [134217728]
//   s    = per-block scale               [32768]
//   z    = per-block zero                [32768]

static constexpr int  COLS      = 2048;
static constexpr long long OUT_ELEMS = 134217728LL;
static constexpr int  NROWS     = 65536;   // 32 * 2048
static constexpr int  NBLK      = 32768;   // 32 * 32 * 32

using v4f = __attribute__((ext_vector_type(4))) float;

// ---------------- Kernel 1: per-row max and 1/sum(exp(x-max)) ----------------
// One wave per row, 4 rows per block. x loads CACHED on purpose: the tail of
// x (~256 MB) stays resident in Infinity Cache for kernel 2's reverse pass.
__global__ __launch_bounds__(256) void rowstats_kernel(
    const float* __restrict__ x, float* __restrict__ stats)
{
    const int lane = threadIdx.x & 63;
    const int wave = threadIdx.x >> 6;
    const long long row = (long long)blockIdx.x * 4 + wave;
    const float* rp = x + row * COLS;

    float4 v[8];
#pragma unroll
    for (int c = 0; c < 8; ++c)
        v[c] = *reinterpret_cast<const float4*>(rp + c * 256 + lane * 4);

    float m = -INFINITY;
#pragma unroll
    for (int c = 0; c < 8; ++c)
        m = fmaxf(m, fmaxf(fmaxf(v[c].x, v[c].y), fmaxf(v[c].z, v[c].w)));
#pragma unroll
    for (int off = 32; off >= 1; off >>= 1)
        m = fmaxf(m, __shfl_xor(m, off, 64));

    float s = 0.0f;
#pragma unroll
    for (int c = 0; c < 8; ++c)
        s += __expf(v[c].x - m) + __expf(v[c].y - m) +
             __expf(v[c].z - m) + __expf(v[c].w - m);
#pragma unroll
    for (int off = 32; off >= 1; off >>= 1)
        s += __shfl_xor(s, off, 64);

    if (lane == 0) {
        stats[row * 2 + 0] = m;
        stats[row * 2 + 1] = 1.0f / s;
    }
}

// ---------------- Kernel 2: 64x256 panel = 4 column-tiles per block ----------
// Processed in REVERSE block order so the first panels read the x region
// kernel 1 touched last (still L3-resident). x loads nontemporal (read-once),
// stores nontemporal (don't evict resident x).
__global__ __launch_bounds__(256) void panel_kernel(
    const float* __restrict__ x, const float* __restrict__ stats,
    float* __restrict__ out, float* __restrict__ qout,
    float* __restrict__ sout, float* __restrict__ zout)
{
    const int b  = 8191 - blockIdx.x;  // reverse traversal
    const int n  = b >> 8;             // 0..31
    const int i  = (b >> 3) & 31;      // row-block
    const int jg = b & 7;              // group of 4 column-tiles
    const int t  = threadIdx.x;
    const int w  = t >> 6;             // wave 0..3
    const int l  = t & 63;

    const long long xbase = (long long)n * (COLS * (long long)COLS)
                          + (long long)(i * 64) * COLS + jg * 256;
    const int growbase = (n << 11) + i * 64;

    float4 p[16];
    float mn = INFINITY, mx = -INFINITY;
#pragma unroll
    for (int k = 0; k < 16; ++k) {
        const int r = (k << 2) + w;
        const float2 st = *reinterpret_cast<const float2*>(
            stats + (long long)(growbase + r) * 2);
        const v4f v = __builtin_nontemporal_load(
            (const v4f*)(x + xbase + (long long)r * COLS + l * 4));
        float4 pv;
        pv.x = __expf(v.x - st.x) * st.y;
        pv.y = __expf(v.y - st.x) * st.y;
        pv.z = __expf(v.z - st.x) * st.y;
        pv.w = __expf(v.w - st.x) * st.y;
        p[k] = pv;
        mn = fminf(mn, fminf(fminf(pv.x, pv.y), fminf(pv.z, pv.w)));
        mx = fmaxf(mx, fmaxf(fmaxf(pv.x, pv.y), fmaxf(pv.z, pv.w)));
    }
    // reduce within each 16-lane group (one group per tile)
#pragma unroll
    for (int off = 8; off >= 1; off >>= 1) {
        mn = fminf(mn, __shfl_xor(mn, off, 64));
        mx = fmaxf(mx, __shfl_xor(mx, off, 64));
    }

    __shared__ float  smn[4][4], smx[4][4];   // [wave][tile]
    __shared__ float2 sbc[4];                 // per tile: {z, 1/(s+eps)}
    if ((l & 15) == 0) { smn[w][l >> 4] = mn; smx[w][l >> 4] = mx; }
    __syncthreads();
    if (t < 4) {
        const float bmn = fminf(fminf(smn[0][t], smn[1][t]),
                                fminf(smn[2][t], smn[3][t]));
        const float bmx = fmaxf(fmaxf(smx[0][t], smx[1][t]),
                                fmaxf(smx[2][t], smx[3][t]));
        const float sc = (bmx - bmn) / 255.0f;
        const float d  = sc + 1e-10f;
        const float zz = -bmn / d - 128.0f;
        const int b4 = (n << 10) + (i << 5) + (jg << 2) + t;
        sout[b4] = sc;
        zout[b4] = zz;
        sbc[t] = make_float2(zz, 1.0f / d);
    }
    __syncthreads();

    const int   tl  = l >> 4;
    const float2 bc = sbc[tl];
    float* __restrict__ qb = qout
        + (long long)((n << 10) + (i << 5) + (jg << 2)) * 4096
        + tl * 4096 + (l & 15) * 4;

#pragma unroll
    for (int k = 0; k < 16; ++k) {
        const int r = (k << 2) + w;
        const float4 pv = p[k];
        __builtin_nontemporal_store(*(const v4f*)&pv,
            (v4f*)(out + xbase + (long long)r * COLS + l * 4));
        float4 qv;
        qv.x = roundf(fminf(fmaxf(pv.x * bc.y + bc.x, -128.0f), 127.0f));
        qv.y = roundf(fminf(fmaxf(pv.y * bc.y + bc.x, -128.0f), 127.0f));
        qv.z = roundf(fminf(fmaxf(pv.z * bc.y + bc.x, -128.0f), 127.0f));
        qv.w = roundf(fminf(fmaxf(pv.w * bc.y + bc.x, -128.0f), 127.0f));
        __builtin_nontemporal_store(*(const v4f*)&qv, (v4f*)(qb + r * 64));
    }
}

extern "C" void kernel_launch(void* const* d_in, const int* in_sizes, int n_in,
                              void* d_out, int out_size, void* d_ws, size_t ws_size,
                              hipStream_t stream) {
    const float* x = (const float*)d_in[0];
    float* out  = (float*)d_out;
    float* qout = out + OUT_ELEMS;
    float* sout = qout + OUT_ELEMS;
    float* zout = sout + NBLK;
    float* stats = (float*)d_ws;   // NROWS * 2 floats = 512 KB

    rowstats_kernel<<<NROWS / 4, 256, 0, stream>>>(x, stats);
    panel_kernel<<<8192, 256, 0, stream>>>(x, stats, out, qout, sout, zout);
}